// Round 5
// baseline (646.591 us; speedup 1.0000x reference)
//
#include <hip/hip_runtime.h>
#include <hip/hip_fp16.h>

#define Q 16
#define EPS 1e-8f
#define DEPTH 5
#define BS 512      // fused_round window/block size
#define WSHIFT 9    // log2(BS)

typedef unsigned int u32;
typedef _Float16 h2 __attribute__((ext_vector_type(2)));

// --- non-temporal helpers: ONLY for read-once streams / write-once outputs.
// Never for random-gather targets (must stay L3-resident) and never for
// scattered stores (NT defeats L2 write-combining: round-3 evidence, +50%).
typedef float f4v __attribute__((ext_vector_type(4)));

__device__ __forceinline__ int nt_ld(const int* p) {
    return __builtin_nontemporal_load(p);
}
__device__ __forceinline__ float4 nt_ldf4(const float4* p) {
    f4v r = __builtin_nontemporal_load((const f4v*)p);
    return make_float4(r.x, r.y, r.z, r.w);
}
__device__ __forceinline__ void nt_stf4(float4* p, float4 v) {
    f4v t; t.x = v.x; t.y = v.y; t.z = v.z; t.w = v.w;
    __builtin_nontemporal_store(t, (f4v*)p);
}

__device__ __forceinline__ u32 pack2(float a, float b) {
    __half2 h = __floats2half2_rn(a, b);
    return *(u32*)&h;
}
__device__ __forceinline__ float2 unpack2(u32 u) {
    __half2 h = *(__half2*)&u;
    return __half22float2(h);
}
__device__ __forceinline__ h2 mkh2(float a, float b) {
    h2 v; v[0] = (_Float16)a; v[1] = (_Float16)b; return v;
}

// ---------- one-time build: dst-sorted slot metadata ----------

// lrd[e] = dst<<16 | local-rank  (dst < 65536, degree < 65536)
// count[n] ends as degree(n). 1.6M fabric atomics ~ transaction floor; accept.
__global__ __launch_bounds__(256) void rank0_kernel(
    const int* __restrict__ dst, int* __restrict__ count,
    int* __restrict__ lrd, int E)
{
    int e = blockIdx.x * 256 + threadIdx.x;
    if (e < E) {
        int d = nt_ld(&dst[e]);
        int r = atomicAdd(&count[d], 1);
        lrd[e] = (int)(((u32)d << 16) | (u32)r);   // cached: gather target later
    }
}

// --- parallel exclusive scan: count[0..N) -> start[0..N] ---
__global__ __launch_bounds__(256) void scan_partial(
    const int* __restrict__ count, int* __restrict__ partial, int N)
{
    __shared__ int sm[256];
    int i = blockIdx.x * 256 + threadIdx.x;
    sm[threadIdx.x] = (i < N) ? count[i] : 0;
    __syncthreads();
    for (int off = 128; off > 0; off >>= 1) {
        if (threadIdx.x < off) sm[threadIdx.x] += sm[threadIdx.x + off];
        __syncthreads();
    }
    if (threadIdx.x == 0) partial[blockIdx.x] = sm[0];
}

__global__ __launch_bounds__(1024) void scan_top(
    int* __restrict__ partial, int nb)
{
    __shared__ int sm[1024];
    int t = threadIdx.x;
    int v = (t < nb) ? partial[t] : 0;
    sm[t] = v;
    __syncthreads();
    for (int off = 1; off < 1024; off <<= 1) {
        int u = (t >= off) ? sm[t - off] : 0;
        __syncthreads();
        sm[t] += u;
        __syncthreads();
    }
    if (t < nb) partial[t] = sm[t] - v;
}

// scan_final + fused boundary-node detection (saves a separate N-pass):
// boundary node = slot range crosses a BS-slot window, or empty.
__global__ __launch_bounds__(256) void scan_final(
    const int* __restrict__ count, const int* __restrict__ partial,
    int* __restrict__ start, int* __restrict__ blist,
    int* __restrict__ bcount, int N)
{
    __shared__ int sm[256];
    int i = blockIdx.x * 256 + threadIdx.x;
    int v = (i < N) ? count[i] : 0;
    sm[threadIdx.x] = v;
    __syncthreads();
    for (int off = 1; off < 256; off <<= 1) {
        int u = (threadIdx.x >= off) ? sm[threadIdx.x - off] : 0;
        __syncthreads();
        sm[threadIdx.x] += u;
        __syncthreads();
    }
    int excl = sm[threadIdx.x] - v + partial[blockIdx.x];
    if (i < N) {
        start[i] = excl;
        bool need = (v == 0) || ((excl >> WSHIFT) != ((excl + v - 1) >> WSHIFT));
        if (need) {
            int p = atomicAdd(bcount, 1);
            blist[p] = i;
        }
    }
    if (i == N - 1) start[N] = excl + v;
}

// Single-pass slot scatter:
// p   = start[dst[e]] + lr[e]                  (lrd stream + L2-hot start)
// pik = start[dst[ie]] + lr[ie]  via lrd[ie]   (the ONE random gather)
// meta2[p] = (pik, dst<<16|src)  8B  — the per-round hot stream (keep SMALL)
// m0e[p]   = e                   4B  — read only by round 1
__global__ __launch_bounds__(256) void scatter_meta(
    const int* __restrict__ a1_src, const int* __restrict__ indice,
    const int* __restrict__ lrd, const int* __restrict__ start,
    int2* __restrict__ meta2, int* __restrict__ m0e, int E)
{
    int e = blockIdx.x * 256 + threadIdx.x;
    if (e < E) {
        u32 dl = (u32)lrd[e];                       // stream (cached: gather tgt)
        int p = start[dl >> 16] + (int)(dl & 0xffffu);
        int ie = nt_ld(&indice[e]);                 // stream, read-once
        u32 dl2 = (u32)lrd[ie];                     // random gather (cached)
        int pik = start[dl2 >> 16] + (int)(dl2 & 0xffffu);
        int dstsrc = (int)((dl & 0xffff0000u) | (u32)nt_ld(&a1_src[e]));
        meta2[p] = make_int2(pik, dstsrc);          // cached scattered stores
        m0e[p] = e;                                 // (L2 merges partial lines)
    }
}

// per-round: init only boundary-node rows to field
__global__ __launch_bounds__(256) void binit(
    const int* __restrict__ blist, const int* __restrict__ bcount,
    const float* __restrict__ field, float* __restrict__ marg)
{
    int idx = blockIdx.x * 256 + threadIdx.x;
    int cnt = *bcount;
    if (idx >= cnt * 4) return;
    int n = blist[idx >> 2], part = idx & 3;
    ((float4*)(marg + (size_t)n * Q))[part] =
        ((const float4*)(field + (size_t)n * Q))[part];
}

// ---------- fused per-round kernel ----------
// MODE 0: round 1 (reads cav via m0e), writes t2
// MODE 1: mid rounds (reads marg_in/t2_old via meta2), writes t2
// MODE 2: last round (as 1, skips dead t2 write)
// Per-round meta stream is the 8B meta2 (12.8 MB/round); the 16B variant
// (round 4) cost +20 us/round via stream+L3-evict pressure.
template<int MODE>
__global__ __launch_bounds__(BS) void fused_round(
    const int2* __restrict__ meta2, const int* __restrict__ m0e,
    const float* __restrict__ C,
    const float* __restrict__ cav,
    const float* __restrict__ marg_in, const u32* __restrict__ t2_old,
    const int* __restrict__ start, const float* __restrict__ field,
    u32* __restrict__ t2_new, float* __restrict__ marg_out, int E)
{
    __shared__ __align__(16) h2 Csh[Q * 8];   // column-major fp16
    __shared__ float stage[BS * 17];
    __shared__ int s_nfirst, s_nlast;

    const int tid = threadIdx.x;
    const int blo = blockIdx.x * BS;
    const int bhi = min(blo + BS, E);
    const int j = blo + tid;
    const bool act = (j < E);

    // ---- issue ALL global loads first (overlap latency with LDS staging) ----
    int2 meta;
    float4 m0, m1, m2, m3;
    uint4 r0, r1;
    if (act) {
        meta = meta2[j];                             // 8B stream
        if (MODE == 0) {
            const float4* rp = (const float4*)(cav + (size_t)nt_ld(&m0e[j]) * Q);
            m0 = nt_ldf4(rp + 0); m1 = nt_ldf4(rp + 1);   // read-once gather
            m2 = nt_ldf4(rp + 2); m3 = nt_ldf4(rp + 3);
        } else {
            const int src = meta.y & 0xffff;
            const float4* mp = (const float4*)(marg_in + (size_t)src * Q);
            const uint4*  tp = (const uint4*)(t2_old + (size_t)meta.x * 8);
            m0 = mp[0]; m1 = mp[1]; m2 = mp[2]; m3 = mp[3];
            r0 = tp[0]; r1 = tp[1];
        }
    }

    if (tid < 128) {
        int q = tid >> 3, kk = tid & 7;
        Csh[q * 8 + kk] = mkh2(C[(2 * kk) * Q + q], C[(2 * kk + 1) * Q + q]);
    }
    if (act) {
        int mydst = (int)(((u32)meta.y) >> 16);
        if (j == blo)     s_nfirst = mydst;
        if (j == bhi - 1) s_nlast  = mydst;
    }
    __syncthreads();

    float t[Q];
    if (act) {
        h2 uh[8];
        float s, logs;
        if (MODE == 0) {
            uh[0] = mkh2(m0.x, m0.y); uh[1] = mkh2(m0.z, m0.w);
            uh[2] = mkh2(m1.x, m1.y); uh[3] = mkh2(m1.z, m1.w);
            uh[4] = mkh2(m2.x, m2.y); uh[5] = mkh2(m2.z, m2.w);
            uh[6] = mkh2(m3.x, m3.y); uh[7] = mkh2(m3.z, m3.w);
            s = 1.f; logs = 0.f;
        } else {
            float2 p0 = unpack2(r0.x), p1 = unpack2(r0.y),
                   p2 = unpack2(r0.z), p3 = unpack2(r0.w);
            float2 p4 = unpack2(r1.x), p5 = unpack2(r1.y),
                   p6 = unpack2(r1.z), p7 = unpack2(r1.w);

            float x[Q] = {m0.x - p0.x, m0.y - p0.y, m0.z - p1.x, m0.w - p1.y,
                          m1.x - p2.x, m1.y - p2.y, m1.z - p3.x, m1.w - p3.y,
                          m2.x - p4.x, m2.y - p4.y, m2.z - p5.x, m2.w - p5.y,
                          m3.x - p6.x, m3.y - p6.y, m3.z - p7.x, m3.w - p7.y};

            float mx = x[0];
#pragma unroll
            for (int q = 1; q < Q; ++q) mx = fmaxf(mx, x[q]);
            float u[Q];
            s = 0.f;
#pragma unroll
            for (int q = 0; q < Q; ++q) { u[q] = __expf(x[q] - mx); s += u[q]; }
            logs = __logf(s);
#pragma unroll
            for (int k = 0; k < 8; ++k) uh[k] = mkh2(u[2 * k], u[2 * k + 1]);
        }

        const float base = EPS * s;
#pragma unroll
        for (int q = 0; q < Q; ++q) {
            const uint4* cp = (const uint4*)&Csh[q * 8];
            h2 col[8];
            ((uint4*)col)[0] = cp[0];
            ((uint4*)col)[1] = cp[1];
            float acc = base;
#pragma unroll
            for (int kk = 0; kk < 8; ++kk)
                acc = __builtin_amdgcn_fdot2(uh[kk], col[kk], acc, false);
            t[q] = __logf(acc) - logs;
        }

        if (MODE != 2) {
            uint4 w0, w1;
            w0.x = pack2(t[0],  t[1]);  w0.y = pack2(t[2],  t[3]);
            w0.z = pack2(t[4],  t[5]);  w0.w = pack2(t[6],  t[7]);
            w1.x = pack2(t[8],  t[9]);  w1.y = pack2(t[10], t[11]);
            w1.z = pack2(t[12], t[13]); w1.w = pack2(t[14], t[15]);
            // CACHED stream store: t2_new is next round's random-gather target.
            uint4* op = (uint4*)(t2_new + (size_t)j * 8);
            op[0] = w0; op[1] = w1;
        }
    } else {
#pragma unroll
        for (int q = 0; q < Q; ++q) t[q] = 0.f;
    }

#pragma unroll
    for (int q = 0; q < Q; ++q) stage[tid * 17 + q] = t[q];
    __syncthreads();

    const int nfirst = s_nfirst;
    const int ncnt = s_nlast - nfirst + 1;
    for (int k = tid; k < ncnt * Q; k += BS) {
        int ln = k >> 4, q = k & 15;
        int n = nfirst + ln;
        int slo = start[n], shi = start[n + 1];
        int lo = max(slo, blo), hi = min(shi, bhi);
        float s = 0.f;
        for (int sl = lo; sl < hi; ++sl) s += stage[(sl - blo) * 17 + q];
        if (slo >= blo && shi <= bhi)
            marg_out[(size_t)n * Q + q] = s + field[(size_t)n * Q + q];
        else
            atomicAdd(marg_out + (size_t)n * Q + q, s);
    }
}

// final: per node log_softmax
__global__ __launch_bounds__(256) void node_out(
    const float* __restrict__ marg, float* __restrict__ out, int N)
{
    int i = blockIdx.x * 256 + threadIdx.x;
    if (i >= N) return;

    const float4* mp = (const float4*)(marg + (size_t)i * Q);
    float4 m0 = nt_ldf4(mp + 0), m1 = nt_ldf4(mp + 1),
           m2 = nt_ldf4(mp + 2), m3 = nt_ldf4(mp + 3);
    float x[Q] = {m0.x, m0.y, m0.z, m0.w, m1.x, m1.y, m1.z, m1.w,
                  m2.x, m2.y, m2.z, m2.w, m3.x, m3.y, m3.z, m3.w};

    float mx = x[0];
#pragma unroll
    for (int q = 1; q < Q; ++q) mx = fmaxf(mx, x[q]);
    float s = 0.f;
#pragma unroll
    for (int q = 0; q < Q; ++q) s += __expf(x[q] - mx);
    float lse = mx + __logf(s);

    float4* op = (float4*)(out + (size_t)i * Q);
    nt_stf4(op + 0, make_float4(x[0]  - lse, x[1]  - lse, x[2]  - lse, x[3]  - lse));
    nt_stf4(op + 1, make_float4(x[4]  - lse, x[5]  - lse, x[6]  - lse, x[7]  - lse));
    nt_stf4(op + 2, make_float4(x[8]  - lse, x[9]  - lse, x[10] - lse, x[11] - lse));
    nt_stf4(op + 3, make_float4(x[12] - lse, x[13] - lse, x[14] - lse, x[15] - lse));
}

extern "C" void kernel_launch(void* const* d_in, const int* in_sizes, int n_in,
                              void* d_out, int out_size, void* d_ws, size_t ws_size,
                              hipStream_t stream) {
    // inputs: 0 marg_i (dead), 1 cav_ij, 2 C, 3 field_i, 4 edge_dst, 5 a1_src, 6 indice_ij
    const float* cav_in   = (const float*)d_in[1];
    const float* C        = (const float*)d_in[2];
    const float* field_i  = (const float*)d_in[3];
    const int*   edge_dst = (const int*)d_in[4];
    const int*   a1_src   = (const int*)d_in[5];
    const int*   indice   = (const int*)d_in[6];
    float* out = (float*)d_out;

    const int E = in_sizes[4];
    const int N = in_sizes[0] / Q;

    char* ws = (char*)d_ws;
    const size_t t2_bytes   = (size_t)E * 32;            // fp16 rows, 32B each
    const size_t node_bytes = (size_t)N * Q * sizeof(float);
    u32*   t2a    = (u32*)ws;                     ws += t2_bytes;
    u32*   t2b    = (u32*)ws;                     ws += t2_bytes;
    int2*  meta2  = (int2*)ws;                    ws += (size_t)E * 8;
    int*   m0e    = (int*)ws;                     ws += (size_t)E * 4;
    int*   lrd    = (int*)ws;                     ws += (size_t)E * 4;
    float* marg_a = (float*)ws;                   ws += node_bytes;
    float* marg_b = (float*)ws;                   ws += node_bytes;
    int*   count  = (int*)ws;                     ws += (size_t)N * 4;
    int*   bcount = (int*)ws;                     ws += 4;
    int*   start  = (int*)ws;                     ws += (size_t)(N + 1) * 4;
    int*   blist  = (int*)ws;                     ws += (size_t)N * 4;
    int*   partial= (int*)ws;

    const int eb = 256;
    const int eg = (E + eb - 1) / eb;         // blocks over E (256-thread kernels)
    const int fg = (E + BS - 1) / BS;         // blocks for fused_round
    const int ng = (N + eb - 1) / eb;         // #scan blocks (<=1024 required)

    // ---- one-time dst-sorted metadata build ----
    hipMemsetAsync(count, 0, (size_t)N * 4 + 4, stream);   // count + bcount
    rank0_kernel<<<eg, eb, 0, stream>>>(edge_dst, count, lrd, E);
    scan_partial<<<ng, eb, 0, stream>>>(count, partial, N);
    scan_top<<<1, 1024, 0, stream>>>(partial, ng);
    scan_final<<<ng, eb, 0, stream>>>(count, partial, start, blist, bcount, N);
    scatter_meta<<<eg, eb, 0, stream>>>(a1_src, indice, lrd, start, meta2, m0e, E);

    // ---- DEPTH rounds, marg double-buffered ----
    u32* t_cur = t2a;
    u32* t_nxt = t2b;
    float* m_in = marg_b;
    float* m_out = marg_a;
    const int bg = (N * 4 + eb - 1) / eb;

    for (int it = 0; it < DEPTH; ++it) {
        binit<<<bg, eb, 0, stream>>>(blist, bcount, field_i, m_out);
        if (it == 0)
            fused_round<0><<<fg, BS, 0, stream>>>(meta2, m0e, C, cav_in,
                                                  nullptr, nullptr, start, field_i,
                                                  t_cur, m_out, E);
        else if (it != DEPTH - 1)
            fused_round<1><<<fg, BS, 0, stream>>>(meta2, m0e, C, nullptr,
                                                  m_in, t_cur, start, field_i,
                                                  t_nxt, m_out, E);
        else
            fused_round<2><<<fg, BS, 0, stream>>>(meta2, m0e, C, nullptr,
                                                  m_in, t_cur, start, field_i,
                                                  nullptr, m_out, E);
        if (it != 0) { u32* tt = t_cur; t_cur = t_nxt; t_nxt = tt; }
        float* tm = m_in; m_in = m_out; m_out = tm;
    }

    node_out<<<ng, eb, 0, stream>>>(m_in, out, N);
}

// Round 6
// 615.213 us; speedup vs baseline: 1.0510x; 1.0510x over previous
//
#include <hip/hip_runtime.h>
#include <hip/hip_fp16.h>

#define Q 16
#define EPS 1e-8f
#define DEPTH 5
#define BS 512      // fused_round window/block size
#define WSHIFT 9    // log2(BS)

typedef unsigned int u32;
typedef _Float16 h2 __attribute__((ext_vector_type(2)));

// NOTE: no non-temporal accesses anywhere. Measured on this chip:
//  - NT scattered stores: +50% on scatter pass (round 3)
//  - NT random-gather loads: +25% on MODE-0 cav gather (round 5 vs round 2)
//  - NT on pure streams: no measurable gain (round 2 = fastest fused_round)

__device__ __forceinline__ u32 pack2(float a, float b) {
    __half2 h = __floats2half2_rn(a, b);
    return *(u32*)&h;
}
__device__ __forceinline__ float2 unpack2(u32 u) {
    __half2 h = *(__half2*)&u;
    return __half22float2(h);
}
__device__ __forceinline__ h2 mkh2(float a, float b) {
    h2 v; v[0] = (_Float16)a; v[1] = (_Float16)b; return v;
}

// ---------- one-time build: dst-sorted slot metadata ----------

// lrd[e] = dst<<16 | local-rank  (dst < 65536, degree < 65536)
// count[n] ends as degree(n). 1.6M fabric atomics ~ transaction floor; accept.
__global__ __launch_bounds__(256) void rank0_kernel(
    const int* __restrict__ dst, int* __restrict__ count,
    int* __restrict__ lrd, int E)
{
    int e = blockIdx.x * 256 + threadIdx.x;
    if (e < E) {
        int d = dst[e];
        int r = atomicAdd(&count[d], 1);
        lrd[e] = (int)(((u32)d << 16) | (u32)r);
    }
}

// --- parallel exclusive scan: count[0..N) -> start[0..N] ---
__global__ __launch_bounds__(256) void scan_partial(
    const int* __restrict__ count, int* __restrict__ partial, int N)
{
    __shared__ int sm[256];
    int i = blockIdx.x * 256 + threadIdx.x;
    sm[threadIdx.x] = (i < N) ? count[i] : 0;
    __syncthreads();
    for (int off = 128; off > 0; off >>= 1) {
        if (threadIdx.x < off) sm[threadIdx.x] += sm[threadIdx.x + off];
        __syncthreads();
    }
    if (threadIdx.x == 0) partial[blockIdx.x] = sm[0];
}

__global__ __launch_bounds__(1024) void scan_top(
    int* __restrict__ partial, int nb)
{
    __shared__ int sm[1024];
    int t = threadIdx.x;
    int v = (t < nb) ? partial[t] : 0;
    sm[t] = v;
    __syncthreads();
    for (int off = 1; off < 1024; off <<= 1) {
        int u = (t >= off) ? sm[t - off] : 0;
        __syncthreads();
        sm[t] += u;
        __syncthreads();
    }
    if (t < nb) partial[t] = sm[t] - v;
}

// scan_final + fused boundary-node detection (saves a separate N-pass):
// boundary node = slot range crosses a BS-slot window, or empty.
__global__ __launch_bounds__(256) void scan_final(
    const int* __restrict__ count, const int* __restrict__ partial,
    int* __restrict__ start, int* __restrict__ blist,
    int* __restrict__ bcount, int N)
{
    __shared__ int sm[256];
    int i = blockIdx.x * 256 + threadIdx.x;
    int v = (i < N) ? count[i] : 0;
    sm[threadIdx.x] = v;
    __syncthreads();
    for (int off = 1; off < 256; off <<= 1) {
        int u = (threadIdx.x >= off) ? sm[threadIdx.x - off] : 0;
        __syncthreads();
        sm[threadIdx.x] += u;
        __syncthreads();
    }
    int excl = sm[threadIdx.x] - v + partial[blockIdx.x];
    if (i < N) {
        start[i] = excl;
        bool need = (v == 0) || ((excl >> WSHIFT) != ((excl + v - 1) >> WSHIFT));
        if (need) {
            int p = atomicAdd(bcount, 1);
            blist[p] = i;
        }
    }
    if (i == N - 1) start[N] = excl + v;
}

// Single-pass slot scatter:
// p   = start[dst[e]] + lr[e]                  (lrd stream + L2-hot start)
// pik = start[dst[ie]] + lr[ie]  via lrd[ie]   (the ONE random gather)
// meta2[p] = (pik, dst<<16|src)  8B  — the per-round hot stream (keep SMALL)
// m0e[p]   = e                   4B  — read only by round 1
__global__ __launch_bounds__(256) void scatter_meta(
    const int* __restrict__ a1_src, const int* __restrict__ indice,
    const int* __restrict__ lrd, const int* __restrict__ start,
    int2* __restrict__ meta2, int* __restrict__ m0e, int E)
{
    int e = blockIdx.x * 256 + threadIdx.x;
    if (e < E) {
        u32 dl = (u32)lrd[e];                       // stream
        int p = start[dl >> 16] + (int)(dl & 0xffffu);
        int ie = indice[e];                         // stream
        u32 dl2 = (u32)lrd[ie];                     // random gather
        int pik = start[dl2 >> 16] + (int)(dl2 & 0xffffu);
        int dstsrc = (int)((dl & 0xffff0000u) | (u32)a1_src[e]);
        meta2[p] = make_int2(pik, dstsrc);          // cached scattered stores
        m0e[p] = e;                                 // (L2 merges partial lines)
    }
}

// per-round: init only boundary-node rows to field
__global__ __launch_bounds__(256) void binit(
    const int* __restrict__ blist, const int* __restrict__ bcount,
    const float* __restrict__ field, float* __restrict__ marg)
{
    int idx = blockIdx.x * 256 + threadIdx.x;
    int cnt = *bcount;
    if (idx >= cnt * 4) return;
    int n = blist[idx >> 2], part = idx & 3;
    ((float4*)(marg + (size_t)n * Q))[part] =
        ((const float4*)(field + (size_t)n * Q))[part];
}

// ---------- fused per-round kernel ----------
// MODE 0: round 1 (reads cav via m0e), writes t2
// MODE 1: mid rounds (reads marg_in/t2_old via meta2), writes t2
// MODE 2: last round (as 1, skips dead t2 write)
template<int MODE>
__global__ __launch_bounds__(BS) void fused_round(
    const int2* __restrict__ meta2, const int* __restrict__ m0e,
    const float* __restrict__ C,
    const float* __restrict__ cav,
    const float* __restrict__ marg_in, const u32* __restrict__ t2_old,
    const int* __restrict__ start, const float* __restrict__ field,
    u32* __restrict__ t2_new, float* __restrict__ marg_out, int E)
{
    __shared__ __align__(16) h2 Csh[Q * 8];   // column-major fp16
    __shared__ float stage[BS * 17];
    __shared__ int s_nfirst, s_nlast;

    const int tid = threadIdx.x;
    const int blo = blockIdx.x * BS;
    const int bhi = min(blo + BS, E);
    const int j = blo + tid;
    const bool act = (j < E);

    // ---- issue ALL global loads first (overlap latency with LDS staging) ----
    int2 meta;
    float4 m0, m1, m2, m3;
    uint4 r0, r1;
    if (act) {
        meta = meta2[j];                             // 8B stream
        if (MODE == 0) {
            const float4* rp = (const float4*)(cav + (size_t)m0e[j] * Q);
            m0 = rp[0]; m1 = rp[1]; m2 = rp[2]; m3 = rp[3];
        } else {
            const int src = meta.y & 0xffff;
            const float4* mp = (const float4*)(marg_in + (size_t)src * Q);
            const uint4*  tp = (const uint4*)(t2_old + (size_t)meta.x * 8);
            m0 = mp[0]; m1 = mp[1]; m2 = mp[2]; m3 = mp[3];
            r0 = tp[0]; r1 = tp[1];
        }
    }

    if (tid < 128) {
        int q = tid >> 3, kk = tid & 7;
        Csh[q * 8 + kk] = mkh2(C[(2 * kk) * Q + q], C[(2 * kk + 1) * Q + q]);
    }
    if (act) {
        int mydst = (int)(((u32)meta.y) >> 16);
        if (j == blo)     s_nfirst = mydst;
        if (j == bhi - 1) s_nlast  = mydst;
    }
    __syncthreads();

    float t[Q];
    if (act) {
        h2 uh[8];
        float s, logs;
        if (MODE == 0) {
            uh[0] = mkh2(m0.x, m0.y); uh[1] = mkh2(m0.z, m0.w);
            uh[2] = mkh2(m1.x, m1.y); uh[3] = mkh2(m1.z, m1.w);
            uh[4] = mkh2(m2.x, m2.y); uh[5] = mkh2(m2.z, m2.w);
            uh[6] = mkh2(m3.x, m3.y); uh[7] = mkh2(m3.z, m3.w);
            s = 1.f; logs = 0.f;
        } else {
            float2 p0 = unpack2(r0.x), p1 = unpack2(r0.y),
                   p2 = unpack2(r0.z), p3 = unpack2(r0.w);
            float2 p4 = unpack2(r1.x), p5 = unpack2(r1.y),
                   p6 = unpack2(r1.z), p7 = unpack2(r1.w);

            float x[Q] = {m0.x - p0.x, m0.y - p0.y, m0.z - p1.x, m0.w - p1.y,
                          m1.x - p2.x, m1.y - p2.y, m1.z - p3.x, m1.w - p3.y,
                          m2.x - p4.x, m2.y - p4.y, m2.z - p5.x, m2.w - p5.y,
                          m3.x - p6.x, m3.y - p6.y, m3.z - p7.x, m3.w - p7.y};

            float mx = x[0];
#pragma unroll
            for (int q = 1; q < Q; ++q) mx = fmaxf(mx, x[q]);
            float u[Q];
            s = 0.f;
#pragma unroll
            for (int q = 0; q < Q; ++q) { u[q] = __expf(x[q] - mx); s += u[q]; }
            logs = __logf(s);
#pragma unroll
            for (int k = 0; k < 8; ++k) uh[k] = mkh2(u[2 * k], u[2 * k + 1]);
        }

        const float base = EPS * s;
#pragma unroll
        for (int q = 0; q < Q; ++q) {
            const uint4* cp = (const uint4*)&Csh[q * 8];
            h2 col[8];
            ((uint4*)col)[0] = cp[0];
            ((uint4*)col)[1] = cp[1];
            float acc = base;
#pragma unroll
            for (int kk = 0; kk < 8; ++kk)
                acc = __builtin_amdgcn_fdot2(uh[kk], col[kk], acc, false);
            t[q] = __logf(acc) - logs;
        }

        if (MODE != 2) {
            uint4 w0, w1;
            w0.x = pack2(t[0],  t[1]);  w0.y = pack2(t[2],  t[3]);
            w0.z = pack2(t[4],  t[5]);  w0.w = pack2(t[6],  t[7]);
            w1.x = pack2(t[8],  t[9]);  w1.y = pack2(t[10], t[11]);
            w1.z = pack2(t[12], t[13]); w1.w = pack2(t[14], t[15]);
            // cached stream store: t2_new is next round's random-gather target
            uint4* op = (uint4*)(t2_new + (size_t)j * 8);
            op[0] = w0; op[1] = w1;
        }
    } else {
#pragma unroll
        for (int q = 0; q < Q; ++q) t[q] = 0.f;
    }

#pragma unroll
    for (int q = 0; q < Q; ++q) stage[tid * 17 + q] = t[q];
    __syncthreads();

    const int nfirst = s_nfirst;
    const int ncnt = s_nlast - nfirst + 1;
    for (int k = tid; k < ncnt * Q; k += BS) {
        int ln = k >> 4, q = k & 15;
        int n = nfirst + ln;
        int slo = start[n], shi = start[n + 1];
        int lo = max(slo, blo), hi = min(shi, bhi);
        float s = 0.f;
        for (int sl = lo; sl < hi; ++sl) s += stage[(sl - blo) * 17 + q];
        if (slo >= blo && shi <= bhi)
            marg_out[(size_t)n * Q + q] = s + field[(size_t)n * Q + q];
        else
            atomicAdd(marg_out + (size_t)n * Q + q, s);
    }
}

// final: per node log_softmax
__global__ __launch_bounds__(256) void node_out(
    const float* __restrict__ marg, float* __restrict__ out, int N)
{
    int i = blockIdx.x * 256 + threadIdx.x;
    if (i >= N) return;

    const float4* mp = (const float4*)(marg + (size_t)i * Q);
    float4 m0 = mp[0], m1 = mp[1], m2 = mp[2], m3 = mp[3];
    float x[Q] = {m0.x, m0.y, m0.z, m0.w, m1.x, m1.y, m1.z, m1.w,
                  m2.x, m2.y, m2.z, m2.w, m3.x, m3.y, m3.z, m3.w};

    float mx = x[0];
#pragma unroll
    for (int q = 1; q < Q; ++q) mx = fmaxf(mx, x[q]);
    float s = 0.f;
#pragma unroll
    for (int q = 0; q < Q; ++q) s += __expf(x[q] - mx);
    float lse = mx + __logf(s);

    float4* op = (float4*)(out + (size_t)i * Q);
    op[0] = make_float4(x[0]  - lse, x[1]  - lse, x[2]  - lse, x[3]  - lse);
    op[1] = make_float4(x[4]  - lse, x[5]  - lse, x[6]  - lse, x[7]  - lse);
    op[2] = make_float4(x[8]  - lse, x[9]  - lse, x[10] - lse, x[11] - lse);
    op[3] = make_float4(x[12] - lse, x[13] - lse, x[14] - lse, x[15] - lse);
}

extern "C" void kernel_launch(void* const* d_in, const int* in_sizes, int n_in,
                              void* d_out, int out_size, void* d_ws, size_t ws_size,
                              hipStream_t stream) {
    // inputs: 0 marg_i (dead), 1 cav_ij, 2 C, 3 field_i, 4 edge_dst, 5 a1_src, 6 indice_ij
    const float* cav_in   = (const float*)d_in[1];
    const float* C        = (const float*)d_in[2];
    const float* field_i  = (const float*)d_in[3];
    const int*   edge_dst = (const int*)d_in[4];
    const int*   a1_src   = (const int*)d_in[5];
    const int*   indice   = (const int*)d_in[6];
    float* out = (float*)d_out;

    const int E = in_sizes[4];
    const int N = in_sizes[0] / Q;

    char* ws = (char*)d_ws;
    const size_t t2_bytes   = (size_t)E * 32;            // fp16 rows, 32B each
    const size_t node_bytes = (size_t)N * Q * sizeof(float);
    u32*   t2a    = (u32*)ws;                     ws += t2_bytes;
    u32*   t2b    = (u32*)ws;                     ws += t2_bytes;
    int2*  meta2  = (int2*)ws;                    ws += (size_t)E * 8;
    int*   m0e    = (int*)ws;                     ws += (size_t)E * 4;
    int*   lrd    = (int*)ws;                     ws += (size_t)E * 4;
    float* marg_a = (float*)ws;                   ws += node_bytes;
    float* marg_b = (float*)ws;                   ws += node_bytes;
    int*   count  = (int*)ws;                     ws += (size_t)N * 4;
    int*   bcount = (int*)ws;                     ws += 4;
    int*   start  = (int*)ws;                     ws += (size_t)(N + 1) * 4;
    int*   blist  = (int*)ws;                     ws += (size_t)N * 4;
    int*   partial= (int*)ws;

    const int eb = 256;
    const int eg = (E + eb - 1) / eb;         // blocks over E (256-thread kernels)
    const int fg = (E + BS - 1) / BS;         // blocks for fused_round
    const int ng = (N + eb - 1) / eb;         // #scan blocks (<=1024 required)

    // ---- one-time dst-sorted metadata build ----
    hipMemsetAsync(count, 0, (size_t)N * 4 + 4, stream);   // count + bcount
    rank0_kernel<<<eg, eb, 0, stream>>>(edge_dst, count, lrd, E);
    scan_partial<<<ng, eb, 0, stream>>>(count, partial, N);
    scan_top<<<1, 1024, 0, stream>>>(partial, ng);
    scan_final<<<ng, eb, 0, stream>>>(count, partial, start, blist, bcount, N);
    scatter_meta<<<eg, eb, 0, stream>>>(a1_src, indice, lrd, start, meta2, m0e, E);

    // ---- DEPTH rounds, marg double-buffered ----
    u32* t_cur = t2a;
    u32* t_nxt = t2b;
    float* m_in = marg_b;
    float* m_out = marg_a;
    const int bg = (N * 4 + eb - 1) / eb;

    for (int it = 0; it < DEPTH; ++it) {
        binit<<<bg, eb, 0, stream>>>(blist, bcount, field_i, m_out);
        if (it == 0)
            fused_round<0><<<fg, BS, 0, stream>>>(meta2, m0e, C, cav_in,
                                                  nullptr, nullptr, start, field_i,
                                                  t_cur, m_out, E);
        else if (it != DEPTH - 1)
            fused_round<1><<<fg, BS, 0, stream>>>(meta2, m0e, C, nullptr,
                                                  m_in, t_cur, start, field_i,
                                                  t_nxt, m_out, E);
        else
            fused_round<2><<<fg, BS, 0, stream>>>(meta2, m0e, C, nullptr,
                                                  m_in, t_cur, start, field_i,
                                                  nullptr, m_out, E);
        if (it != 0) { u32* tt = t_cur; t_cur = t_nxt; t_nxt = tt; }
        float* tm = m_in; m_in = m_out; m_out = tm;
    }

    node_out<<<ng, eb, 0, stream>>>(m_in, out, N);
}

// Round 7
// 601.420 us; speedup vs baseline: 1.0751x; 1.0229x over previous
//
#include <hip/hip_runtime.h>
#include <hip/hip_fp16.h>

#define Q 16
#define EPS 1e-8f
#define DEPTH 5
#define BS 512      // round-kernel window/block size
#define WSHIFT 9    // log2(BS)

typedef unsigned int u32;
typedef _Float16 h2 __attribute__((ext_vector_type(2)));

// NOTE: no non-temporal accesses anywhere. Measured on this chip:
//  - NT scattered stores: +50% on scatter pass (round 3)
//  - NT random-gather loads: +25% on cav gather (round 5 vs round 2)
//  - NT on pure streams: no measurable gain (round 2 = fastest fused_round)

__device__ __forceinline__ u32 pack2(float a, float b) {
    __half2 h = __floats2half2_rn(a, b);
    return *(u32*)&h;
}
__device__ __forceinline__ float2 unpack2(u32 u) {
    __half2 h = *(__half2*)&u;
    return __half22float2(h);
}
__device__ __forceinline__ h2 mkh2(float a, float b) {
    h2 v; v[0] = (_Float16)a; v[1] = (_Float16)b; return v;
}

// ---------- one-time build: dst-sorted slot metadata ----------

// lrd[e] = dst<<16 | local-rank  (dst < 65536, degree < 65536)
// count[n] ends as degree(n). 1.6M fabric atomics ~ transaction floor; accept.
__global__ __launch_bounds__(256) void rank0_kernel(
    const int* __restrict__ dst, int* __restrict__ count,
    int* __restrict__ lrd, int E)
{
    int e = blockIdx.x * 256 + threadIdx.x;
    if (e < E) {
        int d = dst[e];
        int r = atomicAdd(&count[d], 1);
        lrd[e] = (int)(((u32)d << 16) | (u32)r);
    }
}

// --- parallel exclusive scan: count[0..N) -> start[0..N] ---
__global__ __launch_bounds__(256) void scan_partial(
    const int* __restrict__ count, int* __restrict__ partial, int N)
{
    __shared__ int sm[256];
    int i = blockIdx.x * 256 + threadIdx.x;
    sm[threadIdx.x] = (i < N) ? count[i] : 0;
    __syncthreads();
    for (int off = 128; off > 0; off >>= 1) {
        if (threadIdx.x < off) sm[threadIdx.x] += sm[threadIdx.x + off];
        __syncthreads();
    }
    if (threadIdx.x == 0) partial[blockIdx.x] = sm[0];
}

__global__ __launch_bounds__(1024) void scan_top(
    int* __restrict__ partial, int nb)
{
    __shared__ int sm[1024];
    int t = threadIdx.x;
    int v = (t < nb) ? partial[t] : 0;
    sm[t] = v;
    __syncthreads();
    for (int off = 1; off < 1024; off <<= 1) {
        int u = (t >= off) ? sm[t - off] : 0;
        __syncthreads();
        sm[t] += u;
        __syncthreads();
    }
    if (t < nb) partial[t] = sm[t] - v;
}

// scan_final + fused boundary-node detection:
// boundary node = slot range crosses a BS-slot window, or empty.
__global__ __launch_bounds__(256) void scan_final(
    const int* __restrict__ count, const int* __restrict__ partial,
    int* __restrict__ start, int* __restrict__ blist,
    int* __restrict__ bcount, int N)
{
    __shared__ int sm[256];
    int i = blockIdx.x * 256 + threadIdx.x;
    int v = (i < N) ? count[i] : 0;
    sm[threadIdx.x] = v;
    __syncthreads();
    for (int off = 1; off < 256; off <<= 1) {
        int u = (threadIdx.x >= off) ? sm[threadIdx.x - off] : 0;
        __syncthreads();
        sm[threadIdx.x] += u;
        __syncthreads();
    }
    int excl = sm[threadIdx.x] - v + partial[blockIdx.x];
    if (i < N) {
        start[i] = excl;
        bool need = (v == 0) || ((excl >> WSHIFT) != ((excl + v - 1) >> WSHIFT));
        if (need) {
            int p = atomicAdd(bcount, 1);
            blist[p] = i;
        }
    }
    if (i == N - 1) start[N] = excl + v;
}

// Build scatter + round-1 t2 compute fused:
// cav[e] is a STREAM here (edge order) — computing t2^0 = log(cav@C+eps) in
// this pass eliminates the former MODE-0 random cav gather (a full 75us
// random pass). Scattered line-touches per edge unchanged (meta2[p] + t2a[p]
// replaces meta2[p] + m0e[p]).
__global__ __launch_bounds__(256) void scatter_build(
    const int* __restrict__ a1_src, const int* __restrict__ indice,
    const int* __restrict__ lrd, const int* __restrict__ start,
    const float* __restrict__ cav, const float* __restrict__ C,
    int2* __restrict__ meta2, u32* __restrict__ t2a, int E)
{
    __shared__ __align__(16) h2 Csh[Q * 8];   // column-major fp16

    const int e = blockIdx.x * 256 + threadIdx.x;
    const bool act = (e < E);

    // issue all loads first
    u32 dl = 0; int ie = 0, asrc = 0;
    float4 c0, c1, c2, c3;
    if (act) {
        dl = (u32)lrd[e];
        ie = indice[e];
        asrc = a1_src[e];
        const float4* rp = (const float4*)(cav + (size_t)e * Q);   // stream
        c0 = rp[0]; c1 = rp[1]; c2 = rp[2]; c3 = rp[3];
    }
    if (threadIdx.x < 128) {
        int q = threadIdx.x >> 3, kk = threadIdx.x & 7;
        Csh[q * 8 + kk] = mkh2(C[(2 * kk) * Q + q], C[(2 * kk + 1) * Q + q]);
    }
    __syncthreads();
    if (!act) return;

    u32 dl2 = (u32)lrd[ie];                     // the ONE random gather
    int p   = start[dl  >> 16] + (int)(dl  & 0xffffu);
    int pik = start[dl2 >> 16] + (int)(dl2 & 0xffffu);
    meta2[p] = make_int2(pik, (int)((dl & 0xffff0000u) | (u32)asrc));

    // t2^0 = log(cav @ C + eps)   (round-1 math: s=1, logs=0)
    h2 uh[8];
    uh[0] = mkh2(c0.x, c0.y); uh[1] = mkh2(c0.z, c0.w);
    uh[2] = mkh2(c1.x, c1.y); uh[3] = mkh2(c1.z, c1.w);
    uh[4] = mkh2(c2.x, c2.y); uh[5] = mkh2(c2.z, c2.w);
    uh[6] = mkh2(c3.x, c3.y); uh[7] = mkh2(c3.z, c3.w);

    float t[Q];
#pragma unroll
    for (int q = 0; q < Q; ++q) {
        const uint4* cp = (const uint4*)&Csh[q * 8];
        h2 col[8];
        ((uint4*)col)[0] = cp[0];
        ((uint4*)col)[1] = cp[1];
        float acc = EPS;
#pragma unroll
        for (int kk = 0; kk < 8; ++kk)
            acc = __builtin_amdgcn_fdot2(uh[kk], col[kk], acc, false);
        t[q] = __logf(acc);
    }

    uint4 w0, w1;
    w0.x = pack2(t[0],  t[1]);  w0.y = pack2(t[2],  t[3]);
    w0.z = pack2(t[4],  t[5]);  w0.w = pack2(t[6],  t[7]);
    w1.x = pack2(t[8],  t[9]);  w1.y = pack2(t[10], t[11]);
    w1.z = pack2(t[12], t[13]); w1.w = pack2(t[14], t[15]);
    uint4* op = (uint4*)(t2a + (size_t)p * 8);   // scattered 32B (cached)
    op[0] = w0; op[1] = w1;
}

// per-round: init only boundary-node rows to field
__global__ __launch_bounds__(256) void binit(
    const int* __restrict__ blist, const int* __restrict__ bcount,
    const float* __restrict__ field, float* __restrict__ marg)
{
    int idx = blockIdx.x * 256 + threadIdx.x;
    int cnt = *bcount;
    if (idx >= cnt * 4) return;
    int n = blist[idx >> 2], part = idx & 3;
    ((float4*)(marg + (size_t)n * Q))[part] =
        ((const float4*)(field + (size_t)n * Q))[part];
}

// Round 1: pure streamed segment-sum of t2a (slot order) + field -> marg.
// Replaces the former MODE-0 random pass; all accesses are sequential.
__global__ __launch_bounds__(BS) void segsum_round(
    const int2* __restrict__ meta2, const u32* __restrict__ t2,
    const int* __restrict__ start, const float* __restrict__ field,
    float* __restrict__ marg_out, int E)
{
    __shared__ float stage[BS * 17];
    __shared__ int s_nfirst, s_nlast;

    const int tid = threadIdx.x;
    const int blo = blockIdx.x * BS;
    const int bhi = min(blo + BS, E);
    const int j = blo + tid;
    const bool act = (j < E);

    int2 meta;
    uint4 r0, r1;
    if (act) {
        meta = meta2[j];                              // 8B stream
        const uint4* tp = (const uint4*)(t2 + (size_t)j * 8);   // 32B stream
        r0 = tp[0]; r1 = tp[1];
        int mydst = (int)(((u32)meta.y) >> 16);
        if (j == blo)     s_nfirst = mydst;
        if (j == bhi - 1) s_nlast  = mydst;
    }
    __syncthreads();

    float t[Q];
    if (act) {
        float2 p0 = unpack2(r0.x), p1 = unpack2(r0.y),
               p2 = unpack2(r0.z), p3 = unpack2(r0.w);
        float2 p4 = unpack2(r1.x), p5 = unpack2(r1.y),
               p6 = unpack2(r1.z), p7 = unpack2(r1.w);
        t[0] = p0.x; t[1] = p0.y; t[2]  = p1.x; t[3]  = p1.y;
        t[4] = p2.x; t[5] = p2.y; t[6]  = p3.x; t[7]  = p3.y;
        t[8] = p4.x; t[9] = p4.y; t[10] = p5.x; t[11] = p5.y;
        t[12] = p6.x; t[13] = p6.y; t[14] = p7.x; t[15] = p7.y;
    } else {
#pragma unroll
        for (int q = 0; q < Q; ++q) t[q] = 0.f;
    }

#pragma unroll
    for (int q = 0; q < Q; ++q) stage[tid * 17 + q] = t[q];
    __syncthreads();

    const int nfirst = s_nfirst;
    const int ncnt = s_nlast - nfirst + 1;
    for (int k = tid; k < ncnt * Q; k += BS) {
        int ln = k >> 4, q = k & 15;
        int n = nfirst + ln;
        int slo = start[n], shi = start[n + 1];
        int lo = max(slo, blo), hi = min(shi, bhi);
        float s = 0.f;
        for (int sl = lo; sl < hi; ++sl) s += stage[(sl - blo) * 17 + q];
        if (slo >= blo && shi <= bhi)
            marg_out[(size_t)n * Q + q] = s + field[(size_t)n * Q + q];
        else
            atomicAdd(marg_out + (size_t)n * Q + q, s);
    }
}

// ---------- fused per-round kernel (rounds 2..DEPTH) ----------
// MODE 1: mid rounds (reads marg_in/t2_old via meta2), writes t2
// MODE 2: last round (as 1, skips dead t2 write)
template<int MODE>
__global__ __launch_bounds__(BS) void fused_round(
    const int2* __restrict__ meta2,
    const float* __restrict__ C,
    const float* __restrict__ marg_in, const u32* __restrict__ t2_old,
    const int* __restrict__ start, const float* __restrict__ field,
    u32* __restrict__ t2_new, float* __restrict__ marg_out, int E)
{
    __shared__ __align__(16) h2 Csh[Q * 8];   // column-major fp16
    __shared__ float stage[BS * 17];
    __shared__ int s_nfirst, s_nlast;

    const int tid = threadIdx.x;
    const int blo = blockIdx.x * BS;
    const int bhi = min(blo + BS, E);
    const int j = blo + tid;
    const bool act = (j < E);

    // ---- issue ALL global loads first ----
    int2 meta;
    float4 m0, m1, m2, m3;
    uint4 r0, r1;
    if (act) {
        meta = meta2[j];                             // 8B stream
        const int src = meta.y & 0xffff;
        const float4* mp = (const float4*)(marg_in + (size_t)src * Q);
        const uint4*  tp = (const uint4*)(t2_old + (size_t)meta.x * 8);
        m0 = mp[0]; m1 = mp[1]; m2 = mp[2]; m3 = mp[3];
        r0 = tp[0]; r1 = tp[1];
    }

    if (tid < 128) {
        int q = tid >> 3, kk = tid & 7;
        Csh[q * 8 + kk] = mkh2(C[(2 * kk) * Q + q], C[(2 * kk + 1) * Q + q]);
    }
    if (act) {
        int mydst = (int)(((u32)meta.y) >> 16);
        if (j == blo)     s_nfirst = mydst;
        if (j == bhi - 1) s_nlast  = mydst;
    }
    __syncthreads();

    float t[Q];
    if (act) {
        float2 p0 = unpack2(r0.x), p1 = unpack2(r0.y),
               p2 = unpack2(r0.z), p3 = unpack2(r0.w);
        float2 p4 = unpack2(r1.x), p5 = unpack2(r1.y),
               p6 = unpack2(r1.z), p7 = unpack2(r1.w);

        float x[Q] = {m0.x - p0.x, m0.y - p0.y, m0.z - p1.x, m0.w - p1.y,
                      m1.x - p2.x, m1.y - p2.y, m1.z - p3.x, m1.w - p3.y,
                      m2.x - p4.x, m2.y - p4.y, m2.z - p5.x, m2.w - p5.y,
                      m3.x - p6.x, m3.y - p6.y, m3.z - p7.x, m3.w - p7.y};

        float mx = x[0];
#pragma unroll
        for (int q = 1; q < Q; ++q) mx = fmaxf(mx, x[q]);
        float u[Q];
        float s = 0.f;
#pragma unroll
        for (int q = 0; q < Q; ++q) { u[q] = __expf(x[q] - mx); s += u[q]; }
        float logs = __logf(s);
        h2 uh[8];
#pragma unroll
        for (int k = 0; k < 8; ++k) uh[k] = mkh2(u[2 * k], u[2 * k + 1]);

        const float base = EPS * s;
#pragma unroll
        for (int q = 0; q < Q; ++q) {
            const uint4* cp = (const uint4*)&Csh[q * 8];
            h2 col[8];
            ((uint4*)col)[0] = cp[0];
            ((uint4*)col)[1] = cp[1];
            float acc = base;
#pragma unroll
            for (int kk = 0; kk < 8; ++kk)
                acc = __builtin_amdgcn_fdot2(uh[kk], col[kk], acc, false);
            t[q] = __logf(acc) - logs;
        }

        if (MODE != 2) {
            uint4 w0, w1;
            w0.x = pack2(t[0],  t[1]);  w0.y = pack2(t[2],  t[3]);
            w0.z = pack2(t[4],  t[5]);  w0.w = pack2(t[6],  t[7]);
            w1.x = pack2(t[8],  t[9]);  w1.y = pack2(t[10], t[11]);
            w1.z = pack2(t[12], t[13]); w1.w = pack2(t[14], t[15]);
            // cached stream store: t2_new is next round's random-gather target
            uint4* op = (uint4*)(t2_new + (size_t)j * 8);
            op[0] = w0; op[1] = w1;
        }
    } else {
#pragma unroll
        for (int q = 0; q < Q; ++q) t[q] = 0.f;
    }

#pragma unroll
    for (int q = 0; q < Q; ++q) stage[tid * 17 + q] = t[q];
    __syncthreads();

    const int nfirst = s_nfirst;
    const int ncnt = s_nlast - nfirst + 1;
    for (int k = tid; k < ncnt * Q; k += BS) {
        int ln = k >> 4, q = k & 15;
        int n = nfirst + ln;
        int slo = start[n], shi = start[n + 1];
        int lo = max(slo, blo), hi = min(shi, bhi);
        float s = 0.f;
        for (int sl = lo; sl < hi; ++sl) s += stage[(sl - blo) * 17 + q];
        if (slo >= blo && shi <= bhi)
            marg_out[(size_t)n * Q + q] = s + field[(size_t)n * Q + q];
        else
            atomicAdd(marg_out + (size_t)n * Q + q, s);
    }
}

// final: per node log_softmax
__global__ __launch_bounds__(256) void node_out(
    const float* __restrict__ marg, float* __restrict__ out, int N)
{
    int i = blockIdx.x * 256 + threadIdx.x;
    if (i >= N) return;

    const float4* mp = (const float4*)(marg + (size_t)i * Q);
    float4 m0 = mp[0], m1 = mp[1], m2 = mp[2], m3 = mp[3];
    float x[Q] = {m0.x, m0.y, m0.z, m0.w, m1.x, m1.y, m1.z, m1.w,
                  m2.x, m2.y, m2.z, m2.w, m3.x, m3.y, m3.z, m3.w};

    float mx = x[0];
#pragma unroll
    for (int q = 1; q < Q; ++q) mx = fmaxf(mx, x[q]);
    float s = 0.f;
#pragma unroll
    for (int q = 0; q < Q; ++q) s += __expf(x[q] - mx);
    float lse = mx + __logf(s);

    float4* op = (float4*)(out + (size_t)i * Q);
    op[0] = make_float4(x[0]  - lse, x[1]  - lse, x[2]  - lse, x[3]  - lse);
    op[1] = make_float4(x[4]  - lse, x[5]  - lse, x[6]  - lse, x[7]  - lse);
    op[2] = make_float4(x[8]  - lse, x[9]  - lse, x[10] - lse, x[11] - lse);
    op[3] = make_float4(x[12] - lse, x[13] - lse, x[14] - lse, x[15] - lse);
}

extern "C" void kernel_launch(void* const* d_in, const int* in_sizes, int n_in,
                              void* d_out, int out_size, void* d_ws, size_t ws_size,
                              hipStream_t stream) {
    // inputs: 0 marg_i (dead), 1 cav_ij, 2 C, 3 field_i, 4 edge_dst, 5 a1_src, 6 indice_ij
    const float* cav_in   = (const float*)d_in[1];
    const float* C        = (const float*)d_in[2];
    const float* field_i  = (const float*)d_in[3];
    const int*   edge_dst = (const int*)d_in[4];
    const int*   a1_src   = (const int*)d_in[5];
    const int*   indice   = (const int*)d_in[6];
    float* out = (float*)d_out;

    const int E = in_sizes[4];
    const int N = in_sizes[0] / Q;

    char* ws = (char*)d_ws;
    const size_t t2_bytes   = (size_t)E * 32;            // fp16 rows, 32B each
    const size_t node_bytes = (size_t)N * Q * sizeof(float);
    u32*   t2a    = (u32*)ws;                     ws += t2_bytes;
    u32*   t2b    = (u32*)ws;                     ws += t2_bytes;
    int2*  meta2  = (int2*)ws;                    ws += (size_t)E * 8;
    int*   lrd    = (int*)ws;                     ws += (size_t)E * 4;
    float* marg_a = (float*)ws;                   ws += node_bytes;
    float* marg_b = (float*)ws;                   ws += node_bytes;
    int*   count  = (int*)ws;                     ws += (size_t)N * 4;
    int*   bcount = (int*)ws;                     ws += 4;
    int*   start  = (int*)ws;                     ws += (size_t)(N + 1) * 4;
    int*   blist  = (int*)ws;                     ws += (size_t)N * 4;
    int*   partial= (int*)ws;

    const int eb = 256;
    const int eg = (E + eb - 1) / eb;         // blocks over E (256-thread kernels)
    const int fg = (E + BS - 1) / BS;         // blocks for round kernels
    const int ng = (N + eb - 1) / eb;         // #scan blocks (<=1024 required)

    // ---- one-time dst-sorted metadata build (+ round-1 t2 compute) ----
    hipMemsetAsync(count, 0, (size_t)N * 4 + 4, stream);   // count + bcount
    rank0_kernel<<<eg, eb, 0, stream>>>(edge_dst, count, lrd, E);
    scan_partial<<<ng, eb, 0, stream>>>(count, partial, N);
    scan_top<<<1, 1024, 0, stream>>>(partial, ng);
    scan_final<<<ng, eb, 0, stream>>>(count, partial, start, blist, bcount, N);
    scatter_build<<<eg, eb, 0, stream>>>(a1_src, indice, lrd, start,
                                         cav_in, C, meta2, t2a, E);

    // ---- DEPTH rounds, marg + t2 double-buffered ----
    float* m_in  = marg_b;
    float* m_out = marg_a;
    const int bg = (N * 4 + eb - 1) / eb;

    // round 1: streamed segment-sum of t2a
    binit<<<bg, eb, 0, stream>>>(blist, bcount, field_i, m_out);
    segsum_round<<<fg, BS, 0, stream>>>(meta2, t2a, start, field_i, m_out, E);
    { float* tm = m_in; m_in = m_out; m_out = tm; }

    u32* t_cur = t2a;
    u32* t_nxt = t2b;
    for (int it = 1; it < DEPTH; ++it) {
        binit<<<bg, eb, 0, stream>>>(blist, bcount, field_i, m_out);
        if (it != DEPTH - 1)
            fused_round<1><<<fg, BS, 0, stream>>>(meta2, C, m_in, t_cur, start,
                                                  field_i, t_nxt, m_out, E);
        else
            fused_round<2><<<fg, BS, 0, stream>>>(meta2, C, m_in, t_cur, start,
                                                  field_i, nullptr, m_out, E);
        { u32* tt = t_cur; t_cur = t_nxt; t_nxt = tt; }
        { float* tm = m_in; m_in = m_out; m_out = tm; }
    }

    node_out<<<ng, eb, 0, stream>>>(m_in, out, N);
}